// Round 1
// baseline (329.538 us; speedup 1.0000x reference)
//
#include <hip/hip_runtime.h>

// SilkNNUE: per row r of 131072:
//   h128 = relu( sum_{i<29} emb[x[r,i]] )
//   h2   = h128 @ W2.T + b2            (32)
//   h3   = relu([h2, -h2])             (64)
//   h4   = h3 @ W3.T + b3              (32)
//   h5   = relu([h4, -h4])             (64)
//   out  = h5 @ W4.T                   (1)
//
// Thread-per-row; h processed in 4 chunks of 32 dims so all register arrays
// are statically indexed. Weights read via wave-uniform global addresses ->
// s_load into SGPRs -> v_fmac with SGPR operand (no per-FMA fetch inst).

__global__ __launch_bounds__(256) void nnue_kernel(
    const int*   __restrict__ x,    // (N,32) int32
    const float* __restrict__ emb,  // (7424,128)
    const float* __restrict__ W2,   // (32,128)
    const float* __restrict__ b2,   // (32,)
    const float* __restrict__ W3,   // (32,64)
    const float* __restrict__ b3,   // (32,)
    const float* __restrict__ W4,   // (1,64) -> 64 floats
    float*       __restrict__ out,  // (N,)
    int n)
{
    const int row = blockIdx.x * blockDim.x + threadIdx.x;
    if (row >= n) return;

    // ---- load the 29 indices (first 29 of 32 ints, 7x int4 + 1 scalar) ----
    int idxv[29];
    const int4* xr = (const int4*)(x + (size_t)row * 32);
#pragma unroll
    for (int i = 0; i < 7; ++i) {
        int4 v = xr[i];
        idxv[i * 4 + 0] = v.x;
        idxv[i * 4 + 1] = v.y;
        idxv[i * 4 + 2] = v.z;
        idxv[i * 4 + 3] = v.w;
    }
    idxv[28] = x[(size_t)row * 32 + 28];

    // ---- layer 1 accumulator (32 outputs), init with bias ----
    float h2[32];
#pragma unroll
    for (int j = 0; j < 32; ++j) h2[j] = b2[j];

    // ---- 4 chunks of 32 embedding dims: gather-sum, relu, partial W2 ----
    for (int c = 0; c < 4; ++c) {   // dynamic loop: keeps I-cache footprint small
        float acc[32];
#pragma unroll
        for (int d = 0; d < 32; ++d) acc[d] = 0.0f;

        const float* embc = emb + c * 32;
#pragma unroll
        for (int i = 0; i < 29; ++i) {
            const float4* p = (const float4*)(embc + (size_t)idxv[i] * 128);
#pragma unroll
            for (int k = 0; k < 8; ++k) {
                float4 v = p[k];
                acc[k * 4 + 0] += v.x;
                acc[k * 4 + 1] += v.y;
                acc[k * 4 + 2] += v.z;
                acc[k * 4 + 3] += v.w;
            }
        }
#pragma unroll
        for (int d = 0; d < 32; ++d) acc[d] = fmaxf(acc[d], 0.0f);

        // partial matmul: h2[j] += sum_d acc[d] * W2[j][c*32+d]
        // W2 address is wave-uniform -> scalar loads, SGPR operand in FMA.
        const float* w2c = W2 + c * 32;
#pragma unroll
        for (int j = 0; j < 32; ++j) {
            const float* w2row = w2c + (size_t)j * 128;
#pragma unroll
            for (int d = 0; d < 32; ++d)
                h2[j] = fmaf(acc[d], w2row[d], h2[j]);
        }
    }

    // ---- layer 2: h4 = relu([h2,-h2]) @ W3.T + b3 ----
    float h4[32];
#pragma unroll
    for (int j = 0; j < 32; ++j) h4[j] = b3[j];
#pragma unroll
    for (int k = 0; k < 32; ++k) {
        float a = fmaxf(h2[k],  0.0f);   // relu(h2[k])
        float b = fmaxf(-h2[k], 0.0f);   // relu(-h2[k])
#pragma unroll
        for (int j = 0; j < 32; ++j) {
            h4[j] = fmaf(a, W3[(size_t)j * 64 + k],      h4[j]);
            h4[j] = fmaf(b, W3[(size_t)j * 64 + 32 + k], h4[j]);
        }
    }

    // ---- layer 3: out = relu([h4,-h4]) @ W4.T ----
    float o = 0.0f;
#pragma unroll
    for (int k = 0; k < 32; ++k) {
        o = fmaf(fmaxf(h4[k],  0.0f), W4[k],      o);
        o = fmaf(fmaxf(-h4[k], 0.0f), W4[32 + k], o);
    }
    out[row] = o;
}

extern "C" void kernel_launch(void* const* d_in, const int* in_sizes, int n_in,
                              void* d_out, int out_size, void* d_ws, size_t ws_size,
                              hipStream_t stream) {
    const int*   x   = (const int*)  d_in[0];
    const float* emb = (const float*)d_in[1];
    const float* W2  = (const float*)d_in[2];
    const float* b2  = (const float*)d_in[3];
    const float* W3  = (const float*)d_in[4];
    const float* b3  = (const float*)d_in[5];
    const float* W4  = (const float*)d_in[6];
    float* out = (float*)d_out;

    const int n = out_size;               // 131072 rows, 1 output each
    dim3 block(256);
    dim3 grid((n + 255) / 256);
    hipLaunchKernelGGL(nnue_kernel, grid, block, 0, stream,
                       x, emb, W2, b2, W3, b3, W4, out, n);
}

// Round 2
// 275.955 us; speedup vs baseline: 1.1942x; 1.1942x over previous
//
#include <hip/hip_runtime.h>

// SilkNNUE — coalesced-gather design.
// Phase 1: wave handles 16 rows; lane = dim-pair (128 dims / 64 lanes = float2).
//          Indices are wave-uniform -> readfirstlane -> scalar base + saddr load:
//          one dwordx2 instruction moves an entire 512B emb row (4-8 cache lines
//          vs 64 lines/inst in the thread-per-row version).
// Phase 2a: lane = row (64 rows), wave = output-octet of W2 (4 waves x 8 = 32 out).
//          Weight addresses wave-uniform -> s_load -> SGPR operand in v_fmac.
// Phase 2b: same mapping for W3 + CReLU, layer-4 partial, LDS reduce over 4 waves.

constexpr int RPB = 64;    // rows per block
constexpr int HS  = 130;   // hbuf stride (floats): 128 + 2 pad (breaks pow2 banks)
constexpr int H2S = 34;    // h2buf stride (floats): 32 + 2 pad

__global__ __launch_bounds__(256) void nnue_kernel(
    const int*   __restrict__ x,    // (N,32)
    const float* __restrict__ emb,  // (7424,128)
    const float* __restrict__ W2,   // (32,128)
    const float* __restrict__ b2,   // (32,)
    const float* __restrict__ W3,   // (32,64)
    const float* __restrict__ b3,   // (32,)
    const float* __restrict__ W4,   // (64,)
    float*       __restrict__ out,  // (N,)
    int n)
{
    __shared__ float hbuf[RPB * HS];    // 33280 B
    __shared__ float h2buf[RPB * H2S];  //  8704 B
    __shared__ float obuf[256];         //  1024 B

    const int tid  = threadIdx.x;
    const int lane = tid & 63;
    const int wave = tid >> 6;
    const int row0 = blockIdx.x * RPB;

    // ---------------- Phase 1: coalesced gather-sum -----------------------
    {
        const int wrow0 = __builtin_amdgcn_readfirstlane(row0 + wave * 16);
        for (int r = 0; r < 16; ++r) {
            const int row = wrow0 + r;
            float a0 = 0.f, a1 = 0.f;
            if (row < n) {
                const int* xr = x + (size_t)row * 32;   // wave-uniform pointer
                #pragma unroll
                for (int i = 0; i < 29; ++i) {
                    const int idx = __builtin_amdgcn_readfirstlane(xr[i]);
                    const float2* p = (const float2*)(emb + (size_t)idx * 128);
                    const float2 v = p[lane];           // coalesced 512B/wave
                    a0 += v.x; a1 += v.y;
                }
            }
            *(float2*)&hbuf[(wave * 16 + r) * HS + lane * 2] =
                make_float2(fmaxf(a0, 0.f), fmaxf(a1, 0.f));
        }
    }
    __syncthreads();

    // ---------------- Phase 2a: h2 = relu(h) @ W2.T + b2 ------------------
    {
        const int jq = wave;   // output octet (uniform -> scalar weight loads)
        const int rr = lane;   // row within block
        float acc[8];
        #pragma unroll
        for (int j = 0; j < 8; ++j) acc[j] = b2[jq * 8 + j];
        const float* hrow = &hbuf[rr * HS];
        #pragma unroll
        for (int d2 = 0; d2 < 64; ++d2) {
            const float2 v = *(const float2*)&hrow[d2 * 2];
            #pragma unroll
            for (int j = 0; j < 8; ++j) {
                const float* w = W2 + (size_t)(jq * 8 + j) * 128 + d2 * 2;
                acc[j] = fmaf(v.x, w[0], acc[j]);
                acc[j] = fmaf(v.y, w[1], acc[j]);
            }
        }
        #pragma unroll
        for (int j = 0; j < 4; ++j)
            *(float2*)&h2buf[rr * H2S + jq * 8 + 2 * j] =
                make_float2(acc[2 * j], acc[2 * j + 1]);
    }
    __syncthreads();

    // ------- Phase 2b: h4 = crelu(h2) @ W3.T + b3 ; layer-4 partial -------
    {
        const int jq = wave;
        const int rr = lane;
        float acc[8];
        #pragma unroll
        for (int j = 0; j < 8; ++j) acc[j] = b3[jq * 8 + j];
        const float* h2row = &h2buf[rr * H2S];
        #pragma unroll
        for (int k2 = 0; k2 < 16; ++k2) {
            const float2 v = *(const float2*)&h2row[k2 * 2];
            const float p0 = fmaxf(v.x, 0.f), m0 = fmaxf(-v.x, 0.f);
            const float p1 = fmaxf(v.y, 0.f), m1 = fmaxf(-v.y, 0.f);
            #pragma unroll
            for (int j = 0; j < 8; ++j) {
                const float* w = W3 + (size_t)(jq * 8 + j) * 64;
                acc[j] = fmaf(p0, w[2 * k2],          acc[j]);
                acc[j] = fmaf(p1, w[2 * k2 + 1],      acc[j]);
                acc[j] = fmaf(m0, w[32 + 2 * k2],     acc[j]);
                acc[j] = fmaf(m1, w[32 + 2 * k2 + 1], acc[j]);
            }
        }
        float o = 0.f;
        #pragma unroll
        for (int j = 0; j < 8; ++j) {
            const int jj = jq * 8 + j;
            o = fmaf(fmaxf(acc[j], 0.f),  W4[jj],      o);
            o = fmaf(fmaxf(-acc[j], 0.f), W4[32 + jj], o);
        }
        obuf[jq * 64 + rr] = o;
    }
    __syncthreads();

    // ---------------- final reduce + store --------------------------------
    if (tid < 64) {
        const int row = row0 + tid;
        if (row < n)
            out[row] = obuf[tid] + obuf[64 + tid] + obuf[128 + tid] + obuf[192 + tid];
    }
}

extern "C" void kernel_launch(void* const* d_in, const int* in_sizes, int n_in,
                              void* d_out, int out_size, void* d_ws, size_t ws_size,
                              hipStream_t stream) {
    const int*   x   = (const int*)  d_in[0];
    const float* emb = (const float*)d_in[1];
    const float* W2  = (const float*)d_in[2];
    const float* b2  = (const float*)d_in[3];
    const float* W3  = (const float*)d_in[4];
    const float* b3  = (const float*)d_in[5];
    const float* W4  = (const float*)d_in[6];
    float* out = (float*)d_out;

    const int n = out_size;                 // 131072 rows
    dim3 block(256);
    dim3 grid((n + RPB - 1) / RPB);         // 2048 blocks
    hipLaunchKernelGGL(nnue_kernel, grid, block, 0, stream,
                       x, emb, W2, b2, W3, b3, W4, out, n);
}

// Round 3
// 268.729 us; speedup vs baseline: 1.2263x; 1.0269x over previous
//
#include <hip/hip_runtime.h>

// SilkNNUE R2 — MLP-maximized gather + overlap-friendly structure.
// Block = 512 threads (8 waves) handles 64 rows.
// Phase 1: wave w gathers rows w*8..w*8+7; per row, all 29 coalesced float2
//          loads issue into a register array BEFORE any accumulation (batch
//          issue -> tree sum) to keep ~29 loads in flight per wave.
// Phase 2a: wave w computes W2 outputs 4w..4w+3 for all 64 rows (lane=row);
//          weights wave-uniform -> SGPR operands. hbufT transposed+padded:
//          all LDS accesses <=2-way (free).
// Phase 2b: same mapping for W3 + CReLU + W4 partial; LDS reduce over 8 waves.

constexpr int RPB = 64;   // rows per block

__global__ __launch_bounds__(512, 4) void nnue_kernel(
    const int*   __restrict__ x,    // (N,32)
    const float* __restrict__ emb,  // (7424,128)
    const float* __restrict__ W2,   // (32,128)
    const float* __restrict__ b2,   // (32,)
    const float* __restrict__ W3,   // (32,64)
    const float* __restrict__ b3,   // (32,)
    const float* __restrict__ W4,   // (64,)
    float*       __restrict__ out,  // (N,)
    int n)
{
    // transposed h: [dim-pair d2][row], row-stride 65 float2 (pad -> 2-way max)
    __shared__ float2 hbufT[64 * 65];   // 33280 B
    // transposed h2: [out j][row], stride 66 floats
    __shared__ float  h2T[32 * 66];     //  8448 B
    // per-wave layer-4 partials: [wave][row], stride 66
    __shared__ float  obuf[8 * 66];     //  2112 B

    const int tid  = threadIdx.x;
    const int lane = tid & 63;
    const int wave = tid >> 6;
    const int row0 = blockIdx.x * RPB;

    // ---------------- Phase 1: batched coalesced gather -------------------
    {
        const int wrow0 = __builtin_amdgcn_readfirstlane(row0 + wave * 8);
        for (int r = 0; r < 8; ++r) {
            const int row = wrow0 + r;
            float a0 = 0.f, a1 = 0.f;
            if (row < n) {
                const int* xr = x + (size_t)row * 32;
                int idx[29];
                #pragma unroll
                for (int i = 0; i < 29; ++i)
                    idx[i] = __builtin_amdgcn_readfirstlane(xr[i]);

                // batch-issue all 29 loads, then reduce
                float2 v[29];
                #pragma unroll
                for (int i = 0; i < 29; ++i)
                    v[i] = ((const float2*)(emb + (size_t)idx[i] * 128))[lane];

                float s0a = 0.f, s0b = 0.f, s1a = 0.f, s1b = 0.f;
                #pragma unroll
                for (int i = 0; i < 28; i += 2) {
                    s0a += v[i].x;     s1a += v[i].y;
                    s0b += v[i + 1].x; s1b += v[i + 1].y;
                }
                a0 = s0a + s0b + v[28].x;
                a1 = s1a + s1b + v[28].y;
            }
            hbufT[lane * 65 + (wave * 8 + r)] =
                make_float2(fmaxf(a0, 0.f), fmaxf(a1, 0.f));
        }
    }
    __syncthreads();

    // ---------------- Phase 2a: h2 = relu(h) @ W2.T + b2 ------------------
    {
        const int j0 = wave * 4;   // this wave's 4 output rows of W2
        const int rr = lane;       // row within block
        float acc[4];
        #pragma unroll
        for (int j = 0; j < 4; ++j) acc[j] = b2[j0 + j];

        #pragma unroll
        for (int d2 = 0; d2 < 64; ++d2) {
            const float2 v = hbufT[d2 * 65 + rr];   // conflict-free (2-way)
            #pragma unroll
            for (int j = 0; j < 4; ++j) {
                const float* w = W2 + (size_t)(j0 + j) * 128 + d2 * 2;
                acc[j] = fmaf(v.x, w[0], acc[j]);
                acc[j] = fmaf(v.y, w[1], acc[j]);
            }
        }
        #pragma unroll
        for (int j = 0; j < 4; ++j)
            h2T[(j0 + j) * 66 + rr] = acc[j];
    }
    __syncthreads();

    // ------- Phase 2b: h4 = crelu(h2) @ W3.T + b3 ; W4 partial ------------
    {
        const int j0 = wave * 4;
        const int rr = lane;
        float h2v[32];
        #pragma unroll
        for (int k = 0; k < 32; ++k)
            h2v[k] = h2T[k * 66 + rr];              // conflict-free (2-way)

        float acc[4];
        #pragma unroll
        for (int j = 0; j < 4; ++j) acc[j] = b3[j0 + j];
        #pragma unroll
        for (int k = 0; k < 32; ++k) {
            const float p = fmaxf(h2v[k], 0.f);
            const float m = fmaxf(-h2v[k], 0.f);
            #pragma unroll
            for (int j = 0; j < 4; ++j) {
                const float* w = W3 + (size_t)(j0 + j) * 64;
                acc[j] = fmaf(p, w[k],      acc[j]);
                acc[j] = fmaf(m, w[32 + k], acc[j]);
            }
        }
        float o = 0.f;
        #pragma unroll
        for (int j = 0; j < 4; ++j) {
            const int jj = j0 + j;
            o = fmaf(fmaxf(acc[j], 0.f),  W4[jj],      o);
            o = fmaf(fmaxf(-acc[j], 0.f), W4[32 + jj], o);
        }
        obuf[wave * 66 + rr] = o;
    }
    __syncthreads();

    // ---------------- final reduce over 8 waves + store -------------------
    if (tid < 64) {
        const int row = row0 + tid;
        if (row < n) {
            float o = 0.f;
            #pragma unroll
            for (int w = 0; w < 8; ++w) o += obuf[w * 66 + tid];
            out[row] = o;
        }
    }
}

extern "C" void kernel_launch(void* const* d_in, const int* in_sizes, int n_in,
                              void* d_out, int out_size, void* d_ws, size_t ws_size,
                              hipStream_t stream) {
    const int*   x   = (const int*)  d_in[0];
    const float* emb = (const float*)d_in[1];
    const float* W2  = (const float*)d_in[2];
    const float* b2  = (const float*)d_in[3];
    const float* W3  = (const float*)d_in[4];
    const float* b3  = (const float*)d_in[5];
    const float* W4  = (const float*)d_in[6];
    float* out = (float*)d_out;

    const int n = out_size;                 // 131072 rows
    dim3 block(512);
    dim3 grid((n + RPB - 1) / RPB);         // 2048 blocks
    hipLaunchKernelGGL(nnue_kernel, grid, block, 0, stream,
                       x, emb, W2, b2, W3, b3, W4, out, n);
}

// Round 4
// 246.860 us; speedup vs baseline: 1.3349x; 1.0886x over previous
//
#include <hip/hip_runtime.h>
#include <hip/hip_fp16.h>

// SilkNNUE R3 — async fp16 gather via global_load_lds (VGPR-free MLP).
// Pre-pass: emb (7424x128 f32) -> fp16 in d_ws.
// Main: block=256 (4 waves), 64 rows/block; wave handles 16 rows.
//   Per row: 29 async 256B copies emb16[idx] -> LDS slots (vmcnt only, no
//   VGPRs -> compiler can't serialize), s_waitcnt vmcnt(0), fp32 sum from
//   LDS, relu, store h as half2. Indices for all 16 rows pre-loaded into
//   lane registers (2 coalesced dwordx4), fetched per-copy via readlane ->
//   no vector loads inside the loop, so vmcnt(0) waits only on copies.
// Dense phases: wave = 8 outputs, lane = row; weights wave-uniform (SGPR).

#define GLOBAL_AS __attribute__((address_space(1)))
#define LDS_AS    __attribute__((address_space(3)))

constexpr int RPB = 64;   // rows per block

__global__ __launch_bounds__(256) void emb_to_fp16(
    const float* __restrict__ emb, __half2* __restrict__ emb16, int npairs)
{
    int i = blockIdx.x * blockDim.x + threadIdx.x;
    if (i < npairs) {
        float2 v = ((const float2*)emb)[i];
        emb16[i] = __floats2half2_rn(v.x, v.y);
    }
}

__global__ __launch_bounds__(256) void nnue_kernel(
    const int*    __restrict__ x,      // (N,32)
    const __half* __restrict__ emb16,  // (7424,128) fp16
    const float*  __restrict__ W2,     // (32,128)
    const float*  __restrict__ b2,     // (32,)
    const float*  __restrict__ W3,     // (32,64)
    const float*  __restrict__ b3,     // (32,)
    const float*  __restrict__ W4,     // (64,)
    float*        __restrict__ out,    // (N,)
    int n)
{
    __shared__ __half2 slots[4][29][64];   // 29696 B: per-wave copy landing pads
    __shared__ __half2 hbuf[64][65];       // 16640 B: h (post-relu), [row][d2], pad
    __shared__ __half  h2T[32 * 64];       //  4096 B: h2, [j][row]
    // obuf aliases hbuf (hbuf dead after phase 2a)

    const int tid  = threadIdx.x;
    const int lane = tid & 63;
    const int wave = tid >> 6;
    const int row0 = blockIdx.x * RPB;
    const int wrow0 = __builtin_amdgcn_readfirstlane(row0 + wave * 16);

    // ---- load this wave's 16 rows of indices into lane registers ----------
    // element e = r*32+i lives at lane e/8, slot e%8  (r: lanes 4r..4r+3)
    int xv0, xv1, xv2, xv3, xv4, xv5, xv6, xv7;
    {
        const int4* xb = (const int4*)(x + (size_t)wrow0 * 32);
        int4 a = xb[lane * 2];
        int4 b = xb[lane * 2 + 1];
        xv0 = a.x; xv1 = a.y; xv2 = a.z; xv3 = a.w;
        xv4 = b.x; xv5 = b.y; xv6 = b.z; xv7 = b.w;
    }

    // ---- gather loop: async copies -> wait -> sum -------------------------
    for (int r = 0; r < 16; ++r) {
        const int lb = 4 * r;   // base lane holding this row's indices
        #pragma unroll
        for (int i = 0; i < 29; ++i) {
            int idx;
            switch (i & 7) {
                case 0: idx = __builtin_amdgcn_readlane(xv0, lb + (i >> 3)); break;
                case 1: idx = __builtin_amdgcn_readlane(xv1, lb + (i >> 3)); break;
                case 2: idx = __builtin_amdgcn_readlane(xv2, lb + (i >> 3)); break;
                case 3: idx = __builtin_amdgcn_readlane(xv3, lb + (i >> 3)); break;
                case 4: idx = __builtin_amdgcn_readlane(xv4, lb + (i >> 3)); break;
                case 5: idx = __builtin_amdgcn_readlane(xv5, lb + (i >> 3)); break;
                case 6: idx = __builtin_amdgcn_readlane(xv6, lb + (i >> 3)); break;
                default: idx = __builtin_amdgcn_readlane(xv7, lb + (i >> 3)); break;
            }
            const __half2* src = (const __half2*)(emb16 + (size_t)idx * 128) + lane;
            __builtin_amdgcn_global_load_lds((const GLOBAL_AS void*)src,
                                             (LDS_AS void*)&slots[wave][i][0],
                                             4, 0, 0);
        }
        __builtin_amdgcn_s_waitcnt(0x0F70);   // vmcnt(0) only

        float a0 = 0.f, a1 = 0.f;
        #pragma unroll
        for (int i = 0; i < 29; ++i) {
            const __half2 v = slots[wave][i][lane];
            a0 += __low2float(v);
            a1 += __high2float(v);
        }
        hbuf[wave * 16 + r][lane] =
            __floats2half2_rn(fmaxf(a0, 0.f), fmaxf(a1, 0.f));
    }
    __syncthreads();

    // ---- phase 2a: h2 = relu(h) @ W2.T + b2 (wave = 8 outputs, lane = row)
    {
        const int j0 = wave * 8;
        const int rr = lane;
        float acc[8];
        #pragma unroll
        for (int j = 0; j < 8; ++j) acc[j] = b2[j0 + j];
        #pragma unroll
        for (int d2 = 0; d2 < 64; ++d2) {
            const __half2 hv = hbuf[rr][d2];
            const float vx = __low2float(hv), vy = __high2float(hv);
            #pragma unroll
            for (int j = 0; j < 8; ++j) {
                const float* w = W2 + (size_t)(j0 + j) * 128 + d2 * 2;
                acc[j] = fmaf(vx, w[0], acc[j]);
                acc[j] = fmaf(vy, w[1], acc[j]);
            }
        }
        #pragma unroll
        for (int j = 0; j < 8; ++j)
            h2T[(j0 + j) * 64 + rr] = __float2half(acc[j]);
    }
    __syncthreads();

    // ---- phase 2b: h4 = crelu(h2) @ W3.T + b3 ; W4 partial ----------------
    float* obuf = (float*)&hbuf[0][0];   // alias: hbuf dead now
    {
        const int j0 = wave * 8;
        const int rr = lane;
        float h2v[32];
        #pragma unroll
        for (int k = 0; k < 32; ++k) h2v[k] = __half2float(h2T[k * 64 + rr]);

        float acc[8];
        #pragma unroll
        for (int j = 0; j < 8; ++j) acc[j] = b3[j0 + j];
        #pragma unroll
        for (int k = 0; k < 32; ++k) {
            const float p = fmaxf(h2v[k], 0.f);
            const float m = fmaxf(-h2v[k], 0.f);
            #pragma unroll
            for (int j = 0; j < 8; ++j) {
                const float* w = W3 + (size_t)(j0 + j) * 64;
                acc[j] = fmaf(p, w[k],      acc[j]);
                acc[j] = fmaf(m, w[32 + k], acc[j]);
            }
        }
        float o = 0.f;
        #pragma unroll
        for (int j = 0; j < 8; ++j) {
            const int jj = j0 + j;
            o = fmaf(fmaxf(acc[j], 0.f),  W4[jj],      o);
            o = fmaf(fmaxf(-acc[j], 0.f), W4[32 + jj], o);
        }
        obuf[wave * 64 + rr] = o;
    }
    __syncthreads();

    if (tid < 64) {
        const int row = row0 + tid;
        if (row < n)
            out[row] = obuf[tid] + obuf[64 + tid] + obuf[128 + tid] + obuf[192 + tid];
    }
}

extern "C" void kernel_launch(void* const* d_in, const int* in_sizes, int n_in,
                              void* d_out, int out_size, void* d_ws, size_t ws_size,
                              hipStream_t stream) {
    const int*   x   = (const int*)  d_in[0];
    const float* emb = (const float*)d_in[1];
    const float* W2  = (const float*)d_in[2];
    const float* b2  = (const float*)d_in[3];
    const float* W3  = (const float*)d_in[4];
    const float* b3  = (const float*)d_in[5];
    const float* W4  = (const float*)d_in[6];
    float* out = (float*)d_out;

    __half2* emb16 = (__half2*)d_ws;        // 7424*128*2 B = 1.86 MB
    const int npairs = 7424 * 128 / 2;      // 475136 half2
    hipLaunchKernelGGL(emb_to_fp16, dim3((npairs + 255) / 256), dim3(256),
                       0, stream, emb, emb16, npairs);

    const int n = out_size;                 // 131072 rows
    dim3 block(256);
    dim3 grid((n + RPB - 1) / RPB);         // 2048 blocks
    hipLaunchKernelGGL(nnue_kernel, grid, block, 0, stream,
                       x, (const __half*)emb16, W2, b2, W3, b3, W4, out, n);
}

// Round 6
// 201.036 us; speedup vs baseline: 1.6392x; 1.2279x over previous
//
#include <hip/hip_runtime.h>
#include <hip/hip_fp16.h>

// SilkNNUE R5 — wide-lane (16B) register gather, no async tricks.
// Hypothesis: gather is L1/TA lane-request-rate bound (~2 req/cyc/CU, no
// cross-lane coalescing for scattered rows). R3 = 1856 x 4B requests/row;
// R5 = 512 x 16B requests/row (3.6x fewer).
// Layout: lane group g=lane>>4 reads feature 4b+g, bytes (lane&15)*16 ->
// dims 8*(lane&15).. +7, fixed per lane -> fp32 acc[8] in registers; combine
// groups with shfl_xor(16/32); features 29..31 read a zeroed pad row.
// Dense phases unchanged from R3 (verified): wave=8 outputs, lane=row,
// weights wave-uniform -> SGPR operands.

constexpr int RPB = 64;   // rows per block

__global__ __launch_bounds__(256) void emb_to_fp16(
    const float* __restrict__ emb, __half2* __restrict__ emb16,
    int npairs_real, int npairs_tot)
{
    int i = blockIdx.x * blockDim.x + threadIdx.x;
    if (i < npairs_tot) {
        float2 v = make_float2(0.f, 0.f);
        if (i < npairs_real) v = ((const float2*)emb)[i];
        emb16[i] = __floats2half2_rn(v.x, v.y);
    }
}

// readlane of x-element (r,f): element e=r*32+f lives at lane 4r+(f>>3), slot f&7
#define XIDX(r, f)                                                             \
    ((f) >= 29 ? 7424 :                                                        \
     ((f & 7) == 0 ? __builtin_amdgcn_readlane(xa0, 4 * (r) + ((f) >> 3)) :    \
      (f & 7) == 1 ? __builtin_amdgcn_readlane(xa1, 4 * (r) + ((f) >> 3)) :    \
      (f & 7) == 2 ? __builtin_amdgcn_readlane(xa2, 4 * (r) + ((f) >> 3)) :    \
      (f & 7) == 3 ? __builtin_amdgcn_readlane(xa3, 4 * (r) + ((f) >> 3)) :    \
      (f & 7) == 4 ? __builtin_amdgcn_readlane(xb0, 4 * (r) + ((f) >> 3)) :    \
      (f & 7) == 5 ? __builtin_amdgcn_readlane(xb1, 4 * (r) + ((f) >> 3)) :    \
      (f & 7) == 6 ? __builtin_amdgcn_readlane(xb2, 4 * (r) + ((f) >> 3)) :    \
                     __builtin_amdgcn_readlane(xb3, 4 * (r) + ((f) >> 3))))

__global__ __launch_bounds__(256, 4) void nnue_kernel(
    const int*    __restrict__ x,      // (N,32)
    const __half* __restrict__ emb16,  // (7425,128) fp16, row 7424 = zeros
    const float*  __restrict__ W2,     // (32,128)
    const float*  __restrict__ b2,     // (32,)
    const float*  __restrict__ W3,     // (32,64)
    const float*  __restrict__ b3,     // (32,)
    const float*  __restrict__ W4,     // (64,)
    float*        __restrict__ out,    // (N,)
    int n)
{
    __shared__ __half2 hbuf[64][65];   // 16640 B, stride 65 -> conflict-free col reads
    __shared__ float   h2T[32 * 64];   //  8192 B, [j][row]
    __shared__ float   obuf[4][64];    //  1024 B

    const int tid  = threadIdx.x;
    const int lane = tid & 63;
    const int wave = tid >> 6;
    const int row0 = blockIdx.x * RPB;
    const int wrow0 = __builtin_amdgcn_readfirstlane(row0 + wave * 16);

    const int sub = lane & 15;              // 16B slice within feature row
    const unsigned subOff = (unsigned)sub * 16u;
    const bool g0 = (lane & 16) != 0;       // feature-subgroup select bits
    const bool g1 = (lane & 32) != 0;

    // ---- coalesced load of this wave's 16 rows of indices (2048 B) --------
    int xa0, xa1, xa2, xa3, xb0, xb1, xb2, xb3;
    {
        const int4* xb = (const int4*)(x + (size_t)wrow0 * 32);
        int4 a = xb[lane * 2];
        int4 b = xb[lane * 2 + 1];
        xa0 = a.x; xa1 = a.y; xa2 = a.z; xa3 = a.w;
        xb0 = b.x; xb1 = b.y; xb2 = b.z; xb3 = b.w;
    }

    // ---- gather: 8 x dwordx4 per row, fp32 acc, shfl combine --------------
    for (int r = 0; r < 16; ++r) {
        float acc[8];
        #pragma unroll
        for (int q = 0; q < 8; ++q) acc[q] = 0.f;

        uint4 v[8];
        #pragma unroll
        for (int b = 0; b < 8; ++b) {
            const int s0 = XIDX(r, 4 * b + 0);
            const int s1 = XIDX(r, 4 * b + 1);
            const int s2 = XIDX(r, 4 * b + 2);
            const int s3 = XIDX(r, 4 * b + 3);
            const int i01 = g0 ? s1 : s0;
            const int i23 = g0 ? s3 : s2;
            const int idx = g1 ? i23 : i01;
            const unsigned off = ((unsigned)idx << 8) + subOff;
            v[b] = *(const uint4*)((const char*)emb16 + off);
        }
        #pragma unroll
        for (int b = 0; b < 8; ++b) {
            const __half2 h0 = __builtin_bit_cast(__half2, v[b].x);
            const __half2 h1 = __builtin_bit_cast(__half2, v[b].y);
            const __half2 h2 = __builtin_bit_cast(__half2, v[b].z);
            const __half2 h3 = __builtin_bit_cast(__half2, v[b].w);
            acc[0] += __low2float(h0); acc[1] += __high2float(h0);
            acc[2] += __low2float(h1); acc[3] += __high2float(h1);
            acc[4] += __low2float(h2); acc[5] += __high2float(h2);
            acc[6] += __low2float(h3); acc[7] += __high2float(h3);
        }
        // combine the 4 feature-subgroups (lanes differ only in bits 4,5)
        #pragma unroll
        for (int q = 0; q < 8; ++q) {
            acc[q] += __shfl_xor(acc[q], 16);
            acc[q] += __shfl_xor(acc[q], 32);
            acc[q] = fmaxf(acc[q], 0.f);
        }
        if (!g0 && !g1) {   // lanes 0..15 hold the full sums for dims 8*sub..
            const int row = wave * 16 + r;
            #pragma unroll
            for (int q = 0; q < 4; ++q)
                hbuf[row][sub * 4 + q] =
                    __floats2half2_rn(acc[2 * q], acc[2 * q + 1]);
        }
    }
    __syncthreads();

    // ---- phase 2a: h2 = relu(h) @ W2.T + b2 (wave = 8 outputs, lane = row)
    {
        const int j0 = wave * 8;
        const int rr = lane;
        float acc[8];
        #pragma unroll
        for (int j = 0; j < 8; ++j) acc[j] = b2[j0 + j];
        #pragma unroll
        for (int d2 = 0; d2 < 64; ++d2) {
            const __half2 hv = hbuf[rr][d2];
            const float vx = __low2float(hv), vy = __high2float(hv);
            #pragma unroll
            for (int j = 0; j < 8; ++j) {
                const float* w = W2 + (size_t)(j0 + j) * 128 + d2 * 2;
                acc[j] = fmaf(vx, w[0], acc[j]);
                acc[j] = fmaf(vy, w[1], acc[j]);
            }
        }
        #pragma unroll
        for (int j = 0; j < 8; ++j)
            h2T[(j0 + j) * 64 + rr] = acc[j];
    }
    __syncthreads();

    // ---- phase 2b: h4 = crelu(h2) @ W3.T + b3 ; W4 partial ----------------
    {
        const int j0 = wave * 8;
        const int rr = lane;
        float h2v[32];
        #pragma unroll
        for (int k = 0; k < 32; ++k) h2v[k] = h2T[k * 64 + rr];

        float acc[8];
        #pragma unroll
        for (int j = 0; j < 8; ++j) acc[j] = b3[j0 + j];
        #pragma unroll
        for (int k = 0; k < 32; ++k) {
            const float p = fmaxf(h2v[k], 0.f);
            const float m = fmaxf(-h2v[k], 0.f);
            #pragma unroll
            for (int j = 0; j < 8; ++j) {
                const float* w = W3 + (size_t)(j0 + j) * 64;
                acc[j] = fmaf(p, w[k],      acc[j]);
                acc[j] = fmaf(m, w[32 + k], acc[j]);
            }
        }
        float o = 0.f;
        #pragma unroll
        for (int j = 0; j < 8; ++j) {
            const int jj = j0 + j;
            o = fmaf(fmaxf(acc[j], 0.f),  W4[jj],      o);
            o = fmaf(fmaxf(-acc[j], 0.f), W4[32 + jj], o);
        }
        obuf[wave][rr] = o;
    }
    __syncthreads();

    if (tid < 64) {
        const int row = row0 + tid;
        if (row < n)
            out[row] = obuf[0][tid] + obuf[1][tid] + obuf[2][tid] + obuf[3][tid];
    }
}

extern "C" void kernel_launch(void* const* d_in, const int* in_sizes, int n_in,
                              void* d_out, int out_size, void* d_ws, size_t ws_size,
                              hipStream_t stream) {
    const int*   x   = (const int*)  d_in[0];
    const float* emb = (const float*)d_in[1];
    const float* W2  = (const float*)d_in[2];
    const float* b2  = (const float*)d_in[3];
    const float* W3  = (const float*)d_in[4];
    const float* b3  = (const float*)d_in[5];
    const float* W4  = (const float*)d_in[6];
    float* out = (float*)d_out;

    __half2* emb16 = (__half2*)d_ws;        // (7424+1)*128*2 B = 1.9 MB
    const int npairs_real = 7424 * 64;      // real half2 pairs
    const int npairs_tot  = 7425 * 64;      // + zeroed pad row 7424
    hipLaunchKernelGGL(emb_to_fp16, dim3((npairs_tot + 255) / 256), dim3(256),
                       0, stream, emb, emb16, npairs_real, npairs_tot);

    const int n = out_size;                 // 131072 rows
    dim3 block(256);
    dim3 grid((n + RPB - 1) / RPB);         // 2048 blocks
    hipLaunchKernelGGL(nnue_kernel, grid, block, 0, stream,
                       x, (const __half*)emb16, W2, b2, W3, b3, W4, out, n);
}

// Round 8
// 192.564 us; speedup vs baseline: 1.7113x; 1.0440x over previous
//
#include <hip/hip_runtime.h>
#include <hip/hip_fp16.h>

// SilkNNUE R7 — R6 design, compile-fixed: packed fp16 via native _Float16
// ext-vector ops (v_pk_add_f16 / v_pk_max_f16) instead of __hadd2/__hmax2.
//   - fp16 packed accumulate: 32 acc-instr/row vs 128 cvt+add.
//   - indices via LDS broadcast (ds_read_b32, imm offsets); pad features
//     29..31 -> zero-row 7424 at staging.
//   - combine subgroups with 2 packed shfl_xor stages, packed relu.
// Dense phases unchanged (fp32, wave=8 outputs, lane=row, SGPR weights).

typedef _Float16 h2v_t __attribute__((ext_vector_type(2)));

constexpr int RPB = 64;   // rows per block

__global__ __launch_bounds__(256) void emb_to_fp16(
    const float* __restrict__ emb, __half2* __restrict__ emb16,
    int npairs_real, int npairs_tot)
{
    int i = blockIdx.x * blockDim.x + threadIdx.x;
    if (i < npairs_tot) {
        float2 v = make_float2(0.f, 0.f);
        if (i < npairs_real) v = ((const float2*)emb)[i];
        emb16[i] = __floats2half2_rn(v.x, v.y);
    }
}

__global__ __launch_bounds__(256) void nnue_kernel(
    const int*    __restrict__ x,      // (N,32)
    const __half* __restrict__ emb16,  // (7425,128) fp16, row 7424 = zeros
    const float*  __restrict__ W2,     // (32,128)
    const float*  __restrict__ b2,     // (32,)
    const float*  __restrict__ W3,     // (32,64)
    const float*  __restrict__ b3,     // (32,)
    const float*  __restrict__ W4,     // (64,)
    float*        __restrict__ out,    // (N,)
    int n)
{
    __shared__ int     xlds[4][512];   //  8192 B: per-wave 16 rows x 32 idx
    __shared__ __half2 hbuf[64][65];   // 16640 B: stride 65 -> 2-way col reads
    __shared__ float   h2T[32 * 64];   //  8192 B: [j][row]
    __shared__ float   obuf[4][64];    //  1024 B

    const int tid  = threadIdx.x;
    const int lane = tid & 63;
    const int wave = tid >> 6;
    const int row0 = blockIdx.x * RPB;
    const int wrow0 = __builtin_amdgcn_readfirstlane(row0 + wave * 16);

    const int g   = lane >> 4;              // feature subgroup 0..3
    const int sub = lane & 15;              // 16B slice within feature row
    const unsigned subOff = (unsigned)sub * 16u;

    // ---- stage this wave's 16 rows of indices into LDS (pad 29..31) -------
    {
        const int4* xb = (const int4*)(x + (size_t)wrow0 * 32);
        int4 a = xb[lane * 2];
        int4 b = xb[lane * 2 + 1];
        if ((lane & 3) == 3) { b.y = 7424; b.z = 7424; b.w = 7424; }
        ((int4*)&xlds[wave][0])[lane * 2]     = a;
        ((int4*)&xlds[wave][0])[lane * 2 + 1] = b;
    }
    // same-wave DS ops are ordered; no barrier needed.

    // ---- gather: 8 x dwordx4 per row, packed fp16 acc, shfl combine -------
    #pragma unroll 4
    for (int r = 0; r < 16; ++r) {
        const int* xrow = &xlds[wave][r * 32 + g];   // + 4*b via imm offset

        uint4 v[8];
        #pragma unroll
        for (int b = 0; b < 8; ++b) {
            const int idx = xrow[4 * b];             // ds_read_b32, broadcast
            const unsigned off = ((unsigned)idx << 8) + subOff;
            v[b] = *(const uint4*)((const char*)emb16 + off);
        }

        h2v_t hacc[4];
        #pragma unroll
        for (int q = 0; q < 4; ++q) hacc[q] = (h2v_t)0;
        #pragma unroll
        for (int b = 0; b < 8; ++b) {
            hacc[0] += __builtin_bit_cast(h2v_t, v[b].x);
            hacc[1] += __builtin_bit_cast(h2v_t, v[b].y);
            hacc[2] += __builtin_bit_cast(h2v_t, v[b].z);
            hacc[3] += __builtin_bit_cast(h2v_t, v[b].w);
        }
        // combine 4 subgroups (lane bits 4,5) + packed relu
        #pragma unroll
        for (int q = 0; q < 4; ++q) {
            unsigned u = __builtin_bit_cast(unsigned, hacc[q]);
            h2v_t t = __builtin_bit_cast(h2v_t, u);
            t += __builtin_bit_cast(h2v_t, (unsigned)__shfl_xor((int)u, 16));
            unsigned u2 = __builtin_bit_cast(unsigned, t);
            t += __builtin_bit_cast(h2v_t, (unsigned)__shfl_xor((int)u2, 32));
            hacc[q] = __builtin_elementwise_max(t, (h2v_t)0);
        }
        if (g == 0) {   // lanes 0..15 hold full sums for dims 8*sub..8*sub+7
            const int row = wave * 16 + r;
            #pragma unroll
            for (int q = 0; q < 4; ++q)
                hbuf[row][sub * 4 + q] =
                    __builtin_bit_cast(__half2, hacc[q]);
        }
    }
    __syncthreads();

    // ---- phase 2a: h2 = relu(h) @ W2.T + b2 (wave = 8 outputs, lane = row)
    {
        const int j0 = wave * 8;
        const int rr = lane;
        float acc[8];
        #pragma unroll
        for (int j = 0; j < 8; ++j) acc[j] = b2[j0 + j];
        #pragma unroll
        for (int d2 = 0; d2 < 64; ++d2) {
            const __half2 hv = hbuf[rr][d2];
            const float vx = __low2float(hv), vy = __high2float(hv);
            #pragma unroll
            for (int j = 0; j < 8; ++j) {
                const float* w = W2 + (size_t)(j0 + j) * 128 + d2 * 2;
                acc[j] = fmaf(vx, w[0], acc[j]);
                acc[j] = fmaf(vy, w[1], acc[j]);
            }
        }
        #pragma unroll
        for (int j = 0; j < 8; ++j)
            h2T[(j0 + j) * 64 + rr] = acc[j];
    }
    __syncthreads();

    // ---- phase 2b: h4 = crelu(h2) @ W3.T + b3 ; W4 partial ----------------
    {
        const int j0 = wave * 8;
        const int rr = lane;
        float h2v[32];
        #pragma unroll
        for (int k = 0; k < 32; ++k) h2v[k] = h2T[k * 64 + rr];

        float acc[8];
        #pragma unroll
        for (int j = 0; j < 8; ++j) acc[j] = b3[j0 + j];
        #pragma unroll
        for (int k = 0; k < 32; ++k) {
            const float p = fmaxf(h2v[k], 0.f);
            const float m = fmaxf(-h2v[k], 0.f);
            #pragma unroll
            for (int j = 0; j < 8; ++j) {
                const float* w = W3 + (size_t)(j0 + j) * 64;
                acc[j] = fmaf(p, w[k],      acc[j]);
                acc[j] = fmaf(m, w[32 + k], acc[j]);
            }
        }
        float o = 0.f;
        #pragma unroll
        for (int j = 0; j < 8; ++j) {
            const int jj = j0 + j;
            o = fmaf(fmaxf(acc[j], 0.f),  W4[jj],      o);
            o = fmaf(fmaxf(-acc[j], 0.f), W4[32 + jj], o);
        }
        obuf[wave][rr] = o;
    }
    __syncthreads();

    if (tid < 64) {
        const int row = row0 + tid;
        if (row < n)
            out[row] = obuf[0][tid] + obuf[1][tid] + obuf[2][tid] + obuf[3][tid];
    }
}

extern "C" void kernel_launch(void* const* d_in, const int* in_sizes, int n_in,
                              void* d_out, int out_size, void* d_ws, size_t ws_size,
                              hipStream_t stream) {
    const int*   x   = (const int*)  d_in[0];
    const float* emb = (const float*)d_in[1];
    const float* W2  = (const float*)d_in[2];
    const float* b2  = (const float*)d_in[3];
    const float* W3  = (const float*)d_in[4];
    const float* b3  = (const float*)d_in[5];
    const float* W4  = (const float*)d_in[6];
    float* out = (float*)d_out;

    __half2* emb16 = (__half2*)d_ws;        // (7424+1)*128*2 B = 1.9 MB
    const int npairs_real = 7424 * 64;
    const int npairs_tot  = 7425 * 64;
    hipLaunchKernelGGL(emb_to_fp16, dim3((npairs_tot + 255) / 256), dim3(256),
                       0, stream, emb, emb16, npairs_real, npairs_tot);

    const int n = out_size;                 // 131072 rows
    dim3 block(256);
    dim3 grid((n + RPB - 1) / RPB);         // 2048 blocks
    hipLaunchKernelGGL(nnue_kernel, grid, block, 0, stream,
                       x, (const __half*)emb16, W2, b2, W3, b3, W4, out, n);
}

// Round 9
// 172.766 us; speedup vs baseline: 1.9074x; 1.1146x over previous
//
#include <hip/hip_runtime.h>
#include <hip/hip_fp16.h>

// SilkNNUE R8 — split kernels: barrier-free high-occupancy gather + tiny
// thread-per-row dense. Fallback to the R7 fused kernel if ws too small.
//   gather: R7 gather phase only; LDS 8KB, launch_bounds(256,8) -> up to 32
//           waves/CU; h (fp16, post-relu) written to ws, 256B/row.
//   dense:  thread-per-row, h via 16 x dwordx4 (1M requests total - trivial),
//           no LDS, no barriers, weights wave-uniform -> SGPR operands.

typedef _Float16 h2v_t __attribute__((ext_vector_type(2)));

constexpr int RPB = 64;   // rows per block (gather & fused)

__global__ __launch_bounds__(256) void emb_to_fp16(
    const float* __restrict__ emb, __half2* __restrict__ emb16,
    int npairs_real, int npairs_tot)
{
    int i = blockIdx.x * blockDim.x + threadIdx.x;
    if (i < npairs_tot) {
        float2 v = make_float2(0.f, 0.f);
        if (i < npairs_real) v = ((const float2*)emb)[i];
        emb16[i] = __floats2half2_rn(v.x, v.y);
    }
}

// ---------------- gather kernel (no barriers) ------------------------------
__global__ __launch_bounds__(256, 8) void gather_kernel(
    const int*    __restrict__ x,      // (N,32)
    const __half* __restrict__ emb16,  // (7425,128), row 7424 zeros
    uint4*        __restrict__ hout,   // (N,16) uint4 = fp16 h, post-relu
    int n)
{
    __shared__ int xlds[4][512];       // 8 KB: per-wave 16 rows x 32 idx

    const int tid  = threadIdx.x;
    const int lane = tid & 63;
    const int wave = tid >> 6;
    const int row0 = blockIdx.x * RPB;
    const int wrow0 = __builtin_amdgcn_readfirstlane(row0 + wave * 16);

    const int g   = lane >> 4;         // feature subgroup 0..3
    const int sub = lane & 15;         // 16B slice within feature row
    const unsigned subOff = (unsigned)sub * 16u;

    {   // stage indices (pad features 29..31 -> zero row 7424)
        const int4* xb = (const int4*)(x + (size_t)wrow0 * 32);
        int4 a = xb[lane * 2];
        int4 b = xb[lane * 2 + 1];
        if ((lane & 3) == 3) { b.y = 7424; b.z = 7424; b.w = 7424; }
        ((int4*)&xlds[wave][0])[lane * 2]     = a;
        ((int4*)&xlds[wave][0])[lane * 2 + 1] = b;
    }
    // same-wave DS ordering; no barrier needed.

    #pragma unroll 4
    for (int r = 0; r < 16; ++r) {
        const int* xrow = &xlds[wave][r * 32 + g];

        uint4 v[8];
        #pragma unroll
        for (int b = 0; b < 8; ++b) {
            const int idx = xrow[4 * b];             // ds_read_b32 broadcast
            const unsigned off = ((unsigned)idx << 8) + subOff;
            v[b] = *(const uint4*)((const char*)emb16 + off);
        }

        h2v_t hacc[4];
        #pragma unroll
        for (int q = 0; q < 4; ++q) hacc[q] = (h2v_t)0;
        #pragma unroll
        for (int b = 0; b < 8; ++b) {
            hacc[0] += __builtin_bit_cast(h2v_t, v[b].x);
            hacc[1] += __builtin_bit_cast(h2v_t, v[b].y);
            hacc[2] += __builtin_bit_cast(h2v_t, v[b].z);
            hacc[3] += __builtin_bit_cast(h2v_t, v[b].w);
        }
        #pragma unroll
        for (int q = 0; q < 4; ++q) {
            unsigned u = __builtin_bit_cast(unsigned, hacc[q]);
            h2v_t t = __builtin_bit_cast(h2v_t, u);
            t += __builtin_bit_cast(h2v_t, (unsigned)__shfl_xor((int)u, 16));
            unsigned u2 = __builtin_bit_cast(unsigned, t);
            t += __builtin_bit_cast(h2v_t, (unsigned)__shfl_xor((int)u2, 32));
            hacc[q] = __builtin_elementwise_max(t, (h2v_t)0);
        }
        if (g == 0) {   // lanes 0..15: dims 8*sub..8*sub+7 -> 16B each
            const int row = wrow0 + r;
            if (row < n) {
                uint4 o;
                o.x = __builtin_bit_cast(unsigned, hacc[0]);
                o.y = __builtin_bit_cast(unsigned, hacc[1]);
                o.z = __builtin_bit_cast(unsigned, hacc[2]);
                o.w = __builtin_bit_cast(unsigned, hacc[3]);
                hout[(size_t)row * 16 + sub] = o;
            }
        }
    }
}

// ---------------- dense kernel (thread-per-row, no LDS) --------------------
__global__ __launch_bounds__(256) void dense_kernel(
    const uint4* __restrict__ hout,  // (N,16) fp16 h
    const float* __restrict__ W2, const float* __restrict__ b2,
    const float* __restrict__ W3, const float* __restrict__ b3,
    const float* __restrict__ W4,
    float*       __restrict__ out, int n)
{
    const int row = blockIdx.x * blockDim.x + threadIdx.x;
    if (row >= n) return;

    float h2[32];
    #pragma unroll
    for (int j = 0; j < 32; ++j) h2[j] = b2[j];

    const uint4* hr = hout + (size_t)row * 16;
    #pragma unroll
    for (int c = 0; c < 16; ++c) {           // 8 dims per chunk
        const uint4 v = hr[c];
        float hd[8];
        #pragma unroll
        for (int q = 0; q < 4; ++q) {
            const unsigned u = (&v.x)[q];
            const h2v_t t = __builtin_bit_cast(h2v_t, u);
            hd[2 * q]     = (float)t.x;
            hd[2 * q + 1] = (float)t.y;
        }
        #pragma unroll
        for (int j = 0; j < 32; ++j) {
            const float* w = W2 + (size_t)j * 128 + c * 8;
            #pragma unroll
            for (int d = 0; d < 8; ++d)
                h2[j] = fmaf(hd[d], w[d], h2[j]);
        }
    }

    float h4[32];
    #pragma unroll
    for (int j = 0; j < 32; ++j) h4[j] = b3[j];
    #pragma unroll
    for (int k = 0; k < 32; ++k) {
        const float p = fmaxf(h2[k],  0.f);
        const float m = fmaxf(-h2[k], 0.f);
        #pragma unroll
        for (int j = 0; j < 32; ++j) {
            h4[j] = fmaf(p, W3[(size_t)j * 64 + k],      h4[j]);
            h4[j] = fmaf(m, W3[(size_t)j * 64 + 32 + k], h4[j]);
        }
    }

    float o = 0.f;
    #pragma unroll
    for (int k = 0; k < 32; ++k) {
        o = fmaf(fmaxf(h4[k],  0.f), W4[k],      o);
        o = fmaf(fmaxf(-h4[k], 0.f), W4[32 + k], o);
    }
    out[row] = o;
}

// ---------------- fused fallback (R7, proven 132 us) -----------------------
__global__ __launch_bounds__(256) void nnue_fused(
    const int*    __restrict__ x,
    const __half* __restrict__ emb16,
    const float*  __restrict__ W2, const float* __restrict__ b2,
    const float*  __restrict__ W3, const float* __restrict__ b3,
    const float*  __restrict__ W4,
    float*        __restrict__ out, int n)
{
    __shared__ int     xlds[4][512];
    __shared__ __half2 hbuf[64][65];
    __shared__ float   h2T[32 * 64];
    __shared__ float   obuf[4][64];

    const int tid  = threadIdx.x;
    const int lane = tid & 63;
    const int wave = tid >> 6;
    const int row0 = blockIdx.x * RPB;
    const int wrow0 = __builtin_amdgcn_readfirstlane(row0 + wave * 16);
    const int g   = lane >> 4;
    const int sub = lane & 15;
    const unsigned subOff = (unsigned)sub * 16u;

    {
        const int4* xb = (const int4*)(x + (size_t)wrow0 * 32);
        int4 a = xb[lane * 2];
        int4 b = xb[lane * 2 + 1];
        if ((lane & 3) == 3) { b.y = 7424; b.z = 7424; b.w = 7424; }
        ((int4*)&xlds[wave][0])[lane * 2]     = a;
        ((int4*)&xlds[wave][0])[lane * 2 + 1] = b;
    }

    #pragma unroll 4
    for (int r = 0; r < 16; ++r) {
        const int* xrow = &xlds[wave][r * 32 + g];
        uint4 v[8];
        #pragma unroll
        for (int b = 0; b < 8; ++b) {
            const int idx = xrow[4 * b];
            const unsigned off = ((unsigned)idx << 8) + subOff;
            v[b] = *(const uint4*)((const char*)emb16 + off);
        }
        h2v_t hacc[4];
        #pragma unroll
        for (int q = 0; q < 4; ++q) hacc[q] = (h2v_t)0;
        #pragma unroll
        for (int b = 0; b < 8; ++b) {
            hacc[0] += __builtin_bit_cast(h2v_t, v[b].x);
            hacc[1] += __builtin_bit_cast(h2v_t, v[b].y);
            hacc[2] += __builtin_bit_cast(h2v_t, v[b].z);
            hacc[3] += __builtin_bit_cast(h2v_t, v[b].w);
        }
        #pragma unroll
        for (int q = 0; q < 4; ++q) {
            unsigned u = __builtin_bit_cast(unsigned, hacc[q]);
            h2v_t t = __builtin_bit_cast(h2v_t, u);
            t += __builtin_bit_cast(h2v_t, (unsigned)__shfl_xor((int)u, 16));
            unsigned u2 = __builtin_bit_cast(unsigned, t);
            t += __builtin_bit_cast(h2v_t, (unsigned)__shfl_xor((int)u2, 32));
            hacc[q] = __builtin_elementwise_max(t, (h2v_t)0);
        }
        if (g == 0) {
            const int row = wave * 16 + r;
            #pragma unroll
            for (int q = 0; q < 4; ++q)
                hbuf[row][sub * 4 + q] = __builtin_bit_cast(__half2, hacc[q]);
        }
    }
    __syncthreads();

    {
        const int j0 = wave * 8;
        const int rr = lane;
        float acc[8];
        #pragma unroll
        for (int j = 0; j < 8; ++j) acc[j] = b2[j0 + j];
        #pragma unroll
        for (int d2 = 0; d2 < 64; ++d2) {
            const __half2 hv = hbuf[rr][d2];
            const float vx = __low2float(hv), vy = __high2float(hv);
            #pragma unroll
            for (int j = 0; j < 8; ++j) {
                const float* w = W2 + (size_t)(j0 + j) * 128 + d2 * 2;
                acc[j] = fmaf(vx, w[0], acc[j]);
                acc[j] = fmaf(vy, w[1], acc[j]);
            }
        }
        #pragma unroll
        for (int j = 0; j < 8; ++j) h2T[(j0 + j) * 64 + rr] = acc[j];
    }
    __syncthreads();

    {
        const int j0 = wave * 8;
        const int rr = lane;
        float h2v[32];
        #pragma unroll
        for (int k = 0; k < 32; ++k) h2v[k] = h2T[k * 64 + rr];
        float acc[8];
        #pragma unroll
        for (int j = 0; j < 8; ++j) acc[j] = b3[j0 + j];
        #pragma unroll
        for (int k = 0; k < 32; ++k) {
            const float p = fmaxf(h2v[k], 0.f);
            const float m = fmaxf(-h2v[k], 0.f);
            #pragma unroll
            for (int j = 0; j < 8; ++j) {
                const float* w = W3 + (size_t)(j0 + j) * 64;
                acc[j] = fmaf(p, w[k],      acc[j]);
                acc[j] = fmaf(m, w[32 + k], acc[j]);
            }
        }
        float o = 0.f;
        #pragma unroll
        for (int j = 0; j < 8; ++j) {
            const int jj = j0 + j;
            o = fmaf(fmaxf(acc[j], 0.f),  W4[jj],      o);
            o = fmaf(fmaxf(-acc[j], 0.f), W4[32 + jj], o);
        }
        obuf[wave][rr] = o;
    }
    __syncthreads();

    if (tid < 64) {
        const int row = row0 + tid;
        if (row < n)
            out[row] = obuf[0][tid] + obuf[1][tid] + obuf[2][tid] + obuf[3][tid];
    }
}

extern "C" void kernel_launch(void* const* d_in, const int* in_sizes, int n_in,
                              void* d_out, int out_size, void* d_ws, size_t ws_size,
                              hipStream_t stream) {
    const int*   x   = (const int*)  d_in[0];
    const float* emb = (const float*)d_in[1];
    const float* W2  = (const float*)d_in[2];
    const float* b2  = (const float*)d_in[3];
    const float* W3  = (const float*)d_in[4];
    const float* b3  = (const float*)d_in[5];
    const float* W4  = (const float*)d_in[6];
    float* out = (float*)d_out;
    const int n = out_size;                 // 131072 rows

    __half2* emb16 = (__half2*)d_ws;        // 7425*256 B = 1.9 MB
    const int npairs_real = 7424 * 64;
    const int npairs_tot  = 7425 * 64;
    hipLaunchKernelGGL(emb_to_fp16, dim3((npairs_tot + 255) / 256), dim3(256),
                       0, stream, emb, emb16, npairs_real, npairs_tot);

    const size_t emb_bytes = (size_t)7425 * 256;          // 1,900,800
    const size_t h_bytes   = (size_t)n * 256;             // 33.5 MB
    const bool   split_ok  = ws_size >= emb_bytes + h_bytes;

    if (split_ok) {
        uint4* hbuf = (uint4*)((char*)d_ws + emb_bytes);
        hipLaunchKernelGGL(gather_kernel, dim3((n + RPB - 1) / RPB), dim3(256),
                           0, stream, x, (const __half*)emb16, hbuf, n);
        hipLaunchKernelGGL(dense_kernel, dim3((n + 255) / 256), dim3(256),
                           0, stream, (const uint4*)hbuf, W2, b2, W3, b3, W4,
                           out, n);
    } else {
        hipLaunchKernelGGL(nnue_fused, dim3((n + RPB - 1) / RPB), dim3(256),
                           0, stream, x, (const __half*)emb16, W2, b2, W3, b3,
                           W4, out, n);
    }
}

// Round 10
// 131.937 us; speedup vs baseline: 2.4977x; 1.3095x over previous
//
#include <hip/hip_runtime.h>
#include <hip/hip_fp16.h>

// SilkNNUE R9 — split kernels; dense rewritten on MFMA.
//   gather: unchanged from R8 (barrier-free, high-occupancy, fp16 h out).
//   dense_mfma: wave = 16 rows. h2 = h @ W2h^T via mfma_f32_16x16x32_f16
//     (A from h buffer, B = W2 fp16 held in VGPRs), CReLU transposed
//     C->A layout through LDS (stride 68 halfs: conflict-free), W3 MFMA,
//     W4 epilogue + shfl_xor reduce. 8192 waves (4x the old TLP), no s_loads.
//   Weights fp16-ized once in a prepass (error budget ~1e-4, thr 9.9e-4).

typedef _Float16 h2v_t  __attribute__((ext_vector_type(2)));
typedef _Float16 half8  __attribute__((ext_vector_type(8)));
typedef float    f32x4  __attribute__((ext_vector_type(4)));

constexpr int RPB = 64;   // rows per block (gather & fused)

__global__ __launch_bounds__(256) void emb_to_fp16(
    const float* __restrict__ emb, __half2* __restrict__ emb16,
    int npairs_real, int npairs_tot)
{
    int i = blockIdx.x * blockDim.x + threadIdx.x;
    if (i < npairs_tot) {
        float2 v = make_float2(0.f, 0.f);
        if (i < npairs_real) v = ((const float2*)emb)[i];
        emb16[i] = __floats2half2_rn(v.x, v.y);
    }
}

__global__ __launch_bounds__(256) void w_to_fp16(
    const float* __restrict__ W2, const float* __restrict__ W3,
    _Float16* __restrict__ W2h, _Float16* __restrict__ W3h)
{
    int i = blockIdx.x * blockDim.x + threadIdx.x;
    if (i < 4096) W2h[i] = (_Float16)W2[i];
    if (i < 2048) W3h[i] = (_Float16)W3[i];
}

// ---------------- gather kernel (unchanged R8) -----------------------------
__global__ __launch_bounds__(256, 8) void gather_kernel(
    const int*    __restrict__ x,
    const __half* __restrict__ emb16,   // (7425,128), row 7424 zeros
    uint4*        __restrict__ hout,    // (N,16) uint4 = fp16 h, post-relu
    int n)
{
    __shared__ int xlds[4][512];

    const int tid  = threadIdx.x;
    const int lane = tid & 63;
    const int wave = tid >> 6;
    const int row0 = blockIdx.x * RPB;
    const int wrow0 = __builtin_amdgcn_readfirstlane(row0 + wave * 16);

    const int g   = lane >> 4;
    const int sub = lane & 15;
    const unsigned subOff = (unsigned)sub * 16u;

    {
        const int4* xb = (const int4*)(x + (size_t)wrow0 * 32);
        int4 a = xb[lane * 2];
        int4 b = xb[lane * 2 + 1];
        if ((lane & 3) == 3) { b.y = 7424; b.z = 7424; b.w = 7424; }
        ((int4*)&xlds[wave][0])[lane * 2]     = a;
        ((int4*)&xlds[wave][0])[lane * 2 + 1] = b;
    }

    #pragma unroll 4
    for (int r = 0; r < 16; ++r) {
        const int* xrow = &xlds[wave][r * 32 + g];
        uint4 v[8];
        #pragma unroll
        for (int b = 0; b < 8; ++b) {
            const int idx = xrow[4 * b];
            const unsigned off = ((unsigned)idx << 8) + subOff;
            v[b] = *(const uint4*)((const char*)emb16 + off);
        }
        h2v_t hacc[4];
        #pragma unroll
        for (int q = 0; q < 4; ++q) hacc[q] = (h2v_t)0;
        #pragma unroll
        for (int b = 0; b < 8; ++b) {
            hacc[0] += __builtin_bit_cast(h2v_t, v[b].x);
            hacc[1] += __builtin_bit_cast(h2v_t, v[b].y);
            hacc[2] += __builtin_bit_cast(h2v_t, v[b].z);
            hacc[3] += __builtin_bit_cast(h2v_t, v[b].w);
        }
        #pragma unroll
        for (int q = 0; q < 4; ++q) {
            unsigned u = __builtin_bit_cast(unsigned, hacc[q]);
            h2v_t t = __builtin_bit_cast(h2v_t, u);
            t += __builtin_bit_cast(h2v_t, (unsigned)__shfl_xor((int)u, 16));
            unsigned u2 = __builtin_bit_cast(unsigned, t);
            t += __builtin_bit_cast(h2v_t, (unsigned)__shfl_xor((int)u2, 32));
            hacc[q] = __builtin_elementwise_max(t, (h2v_t)0);
        }
        if (g == 0) {
            const int row = wrow0 + r;
            if (row < n) {
                uint4 o;
                o.x = __builtin_bit_cast(unsigned, hacc[0]);
                o.y = __builtin_bit_cast(unsigned, hacc[1]);
                o.z = __builtin_bit_cast(unsigned, hacc[2]);
                o.w = __builtin_bit_cast(unsigned, hacc[3]);
                hout[(size_t)row * 16 + sub] = o;
            }
        }
    }
}

// ---------------- dense kernel: MFMA, wave = 16 rows -----------------------
__global__ __launch_bounds__(256) void dense_mfma(
    const uint4*    __restrict__ hbuf,  // (N,16) fp16 h
    const _Float16* __restrict__ W2h,   // (32,128) fp16
    const _Float16* __restrict__ W3h,   // (32,64) fp16
    const float*    __restrict__ b2,
    const float*    __restrict__ b3,
    const float*    __restrict__ W4,    // (64,)
    float*          __restrict__ out, int n)
{
    __shared__ _Float16 a2lds[4][16 * 68];   // per-wave crelu(h2), stride 68

    const int tid  = threadIdx.x;
    const int lane = tid & 63;
    const int wave = tid >> 6;
    const int q    = lane >> 4;     // k-quad
    const int nn   = lane & 15;     // A: row m ; B: col n ; C/D: col n
    const int row0 = blockIdx.x * 64 + wave * 16;

    // ---- B-fragments for W2 (held in VGPRs; identical across waves -> L2 hot)
    half8 bw2[2][4];
    #pragma unroll
    for (int nt = 0; nt < 2; ++nt)
        #pragma unroll
        for (int kk = 0; kk < 4; ++kk)
            bw2[nt][kk] = __builtin_bit_cast(half8,
                *(const uint4*)((const char*)W2h +
                    ((nt * 16 + nn) * 128 + kk * 32 + q * 8) * 2));

    // ---- A-fragments from h (row m = nn, k = kk*32 + q*8 + j) -------------
    const int rowm = min(row0 + nn, n - 1);
    const char* hb = (const char*)hbuf + (size_t)rowm * 256;
    half8 af[4];
    #pragma unroll
    for (int kk = 0; kk < 4; ++kk)
        af[kk] = __builtin_bit_cast(half8,
            *(const uint4*)(hb + kk * 64 + q * 16));

    // ---- layer 2 MFMA: h2(16x32) = h(16x128) @ W2^T ----------------------
    f32x4 acc0 = {0.f, 0.f, 0.f, 0.f}, acc1 = {0.f, 0.f, 0.f, 0.f};
    #pragma unroll
    for (int kk = 0; kk < 4; ++kk) {
        acc0 = __builtin_amdgcn_mfma_f32_16x16x32_f16(af[kk], bw2[0][kk], acc0, 0, 0, 0);
        acc1 = __builtin_amdgcn_mfma_f32_16x16x32_f16(af[kk], bw2[1][kk], acc1, 0, 0, 0);
    }
    const float bb0 = b2[nn], bb1 = b2[16 + nn];

    // ---- CReLU + transpose C-layout -> A-layout via LDS ------------------
    // C: row m = q*4+r, col = nn / 16+nn. A2 row stride 68 halfs (136 B).
    _Float16* a2 = &a2lds[wave][0];
    #pragma unroll
    for (int r = 0; r < 4; ++r) {
        const float v0 = acc0[r] + bb0;
        const float v1 = acc1[r] + bb1;
        const int m = q * 4 + r;
        a2[m * 68 + nn]      = (_Float16)fmaxf(v0, 0.f);
        a2[m * 68 + 16 + nn] = (_Float16)fmaxf(v1, 0.f);
        a2[m * 68 + 32 + nn] = (_Float16)fmaxf(-v0, 0.f);
        a2[m * 68 + 48 + nn] = (_Float16)fmaxf(-v1, 0.f);
    }
    // same-wave LDS write->read: lockstep + compiler lgkmcnt ordering.

    // ---- B-fragments for W3 ----------------------------------------------
    half8 bw3[2][2];
    #pragma unroll
    for (int nt = 0; nt < 2; ++nt)
        #pragma unroll
        for (int kk = 0; kk < 2; ++kk)
            bw3[nt][kk] = __builtin_bit_cast(half8,
                *(const uint4*)((const char*)W3h +
                    ((nt * 16 + nn) * 64 + kk * 32 + q * 8) * 2));

    // ---- A-fragments for layer 3 (m = nn, k = kk*32 + q*8 + j) -----------
    half8 a2f[2];
    #pragma unroll
    for (int kk = 0; kk < 2; ++kk) {
        const _Float16* p = &a2[nn * 68 + kk * 32 + q * 8];
        half8 t;
        #pragma unroll
        for (int j = 0; j < 8; ++j) t[j] = p[j];
        a2f[kk] = t;
    }

    // ---- layer 3 MFMA: h4(16x32) = crelu(h2)(16x64) @ W3^T ---------------
    f32x4 acc30 = {0.f, 0.f, 0.f, 0.f}, acc31 = {0.f, 0.f, 0.f, 0.f};
    #pragma unroll
    for (int kk = 0; kk < 2; ++kk) {
        acc30 = __builtin_amdgcn_mfma_f32_16x16x32_f16(a2f[kk], bw3[0][kk], acc30, 0, 0, 0);
        acc31 = __builtin_amdgcn_mfma_f32_16x16x32_f16(a2f[kk], bw3[1][kk], acc31, 0, 0, 0);
    }
    const float bb30 = b3[nn], bb31 = b3[16 + nn];

    // ---- layer 4: out[m] = crelu(h4[m]) . W4  ----------------------------
    const float w4a = W4[nn],      w4b = W4[16 + nn];
    const float w4c = W4[32 + nn], w4d = W4[48 + nn];
    float o[4];
    #pragma unroll
    for (int r = 0; r < 4; ++r) {
        const float v0 = acc30[r] + bb30;
        const float v1 = acc31[r] + bb31;
        o[r] = fmaxf(v0, 0.f) * w4a + fmaxf(-v0, 0.f) * w4c
             + fmaxf(v1, 0.f) * w4b + fmaxf(-v1, 0.f) * w4d;
    }
    #pragma unroll
    for (int s = 1; s < 16; s <<= 1) {
        #pragma unroll
        for (int r = 0; r < 4; ++r) o[r] += __shfl_xor(o[r], s);
    }
    if (nn == 0) {
        #pragma unroll
        for (int r = 0; r < 4; ++r) {
            const int row = row0 + q * 4 + r;
            if (row < n) out[row] = o[r];
        }
    }
}

// ---------------- fused fallback (R7, proven) ------------------------------
__global__ __launch_bounds__(256) void nnue_fused(
    const int*    __restrict__ x,
    const __half* __restrict__ emb16,
    const float*  __restrict__ W2, const float* __restrict__ b2,
    const float*  __restrict__ W3, const float* __restrict__ b3,
    const float*  __restrict__ W4,
    float*        __restrict__ out, int n)
{
    __shared__ int     xlds[4][512];
    __shared__ __half2 hbuf[64][65];
    __shared__ float   h2T[32 * 64];
    __shared__ float   obuf[4][64];

    const int tid  = threadIdx.x;
    const int lane = tid & 63;
    const int wave = tid >> 6;
    const int row0 = blockIdx.x * RPB;
    const int wrow0 = __builtin_amdgcn_readfirstlane(row0 + wave * 16);
    const int g   = lane >> 4;
    const int sub = lane & 15;
    const unsigned subOff = (unsigned)sub * 16u;

    {
        const int4* xb = (const int4*)(x + (size_t)wrow0 * 32);
        int4 a = xb[lane * 2];
        int4 b = xb[lane * 2 + 1];
        if ((lane & 3) == 3) { b.y = 7424; b.z = 7424; b.w = 7424; }
        ((int4*)&xlds[wave][0])[lane * 2]     = a;
        ((int4*)&xlds[wave][0])[lane * 2 + 1] = b;
    }

    #pragma unroll 4
    for (int r = 0; r < 16; ++r) {
        const int* xrow = &xlds[wave][r * 32 + g];
        uint4 v[8];
        #pragma unroll
        for (int b = 0; b < 8; ++b) {
            const int idx = xrow[4 * b];
            const unsigned off = ((unsigned)idx << 8) + subOff;
            v[b] = *(const uint4*)((const char*)emb16 + off);
        }
        h2v_t hacc[4];
        #pragma unroll
        for (int q = 0; q < 4; ++q) hacc[q] = (h2v_t)0;
        #pragma unroll
        for (int b = 0; b < 8; ++b) {
            hacc[0] += __builtin_bit_cast(h2v_t, v[b].x);
            hacc[1] += __builtin_bit_cast(h2v_t, v[b].y);
            hacc[2] += __builtin_bit_cast(h2v_t, v[b].z);
            hacc[3] += __builtin_bit_cast(h2v_t, v[b].w);
        }
        #pragma unroll
        for (int q = 0; q < 4; ++q) {
            unsigned u = __builtin_bit_cast(unsigned, hacc[q]);
            h2v_t t = __builtin_bit_cast(h2v_t, u);
            t += __builtin_bit_cast(h2v_t, (unsigned)__shfl_xor((int)u, 16));
            unsigned u2 = __builtin_bit_cast(unsigned, t);
            t += __builtin_bit_cast(h2v_t, (unsigned)__shfl_xor((int)u2, 32));
            hacc[q] = __builtin_elementwise_max(t, (h2v_t)0);
        }
        if (g == 0) {
            const int row = wave * 16 + r;
            #pragma unroll
            for (int q = 0; q < 4; ++q)
                hbuf[row][sub * 4 + q] = __builtin_bit_cast(__half2, hacc[q]);
        }
    }
    __syncthreads();

    {
        const int j0 = wave * 8;
        const int rr = lane;
        float acc[8];
        #pragma unroll
        for (int j = 0; j < 8; ++j) acc[j] = b2[j0 + j];
        #pragma unroll
        for (int d2 = 0; d2 < 64; ++d2) {
            const __half2 hv = hbuf[rr][d2];
            const float vx = __low2float(hv), vy = __high2float(hv);
            #pragma unroll
            for (int j = 0; j < 8; ++j) {
                const float* w = W2 + (size_t)(j0 + j) * 128 + d2 * 2;
                acc[j] = fmaf(vx, w[0], acc[j]);
                acc[j] = fmaf(vy, w[1], acc[j]);
            }
        }
        #pragma unroll
        for (int j = 0; j < 8; ++j) h2T[(j0 + j) * 64 + rr] = acc[j];
    }
    __syncthreads();

    {
        const int j0 = wave * 8;
        const int rr = lane;
        float h2v[32];
        #pragma unroll
        for (int k = 0; k < 32; ++k) h2v[k] = h2T[k * 64 + rr];
        float acc[8];
        #pragma unroll
        for (int j = 0; j < 8; ++j) acc[j] = b3[j0 + j];
        #pragma unroll
        for (int k = 0; k < 32; ++k) {
            const float p = fmaxf(h2v[k], 0.f);
            const float m = fmaxf(-h2v[k], 0.f);
            #pragma unroll
            for (int j = 0; j < 8; ++j) {
                const float* w = W3 + (size_t)(j0 + j) * 64;
                acc[j] = fmaf(p, w[k],      acc[j]);
                acc[j] = fmaf(m, w[32 + k], acc[j]);
            }
        }
        float o = 0.f;
        #pragma unroll
        for (int j = 0; j < 8; ++j) {
            const int jj = j0 + j;
            o = fmaf(fmaxf(acc[j], 0.f),  W4[jj],      o);
            o = fmaf(fmaxf(-acc[j], 0.f), W4[32 + jj], o);
        }
        obuf[wave][rr] = o;
    }
    __syncthreads();

    if (tid < 64) {
        const int row = row0 + tid;
        if (row < n)
            out[row] = obuf[0][tid] + obuf[1][tid] + obuf[2][tid] + obuf[3][tid];
    }
}

extern "C" void kernel_launch(void* const* d_in, const int* in_sizes, int n_in,
                              void* d_out, int out_size, void* d_ws, size_t ws_size,
                              hipStream_t stream) {
    const int*   x   = (const int*)  d_in[0];
    const float* emb = (const float*)d_in[1];
    const float* W2  = (const float*)d_in[2];
    const float* b2  = (const float*)d_in[3];
    const float* W3  = (const float*)d_in[4];
    const float* b3  = (const float*)d_in[5];
    const float* W4  = (const float*)d_in[6];
    float* out = (float*)d_out;
    const int n = out_size;                 // 131072 rows

    __half2* emb16 = (__half2*)d_ws;        // 7425*256 B
    const int npairs_real = 7424 * 64;
    const int npairs_tot  = 7425 * 64;
    hipLaunchKernelGGL(emb_to_fp16, dim3((npairs_tot + 255) / 256), dim3(256),
                       0, stream, emb, emb16, npairs_real, npairs_tot);

    const size_t emb_bytes = (size_t)7425 * 256;            // 1,900,800
    const size_t w2h_off   = emb_bytes;                     // 8192 B
    const size_t w3h_off   = w2h_off + 8192;                // 4096 B
    const size_t h_off     = w3h_off + 4096;                // 16B aligned
    const size_t h_bytes   = (size_t)n * 256;
    const bool   split_ok  = ws_size >= h_off + h_bytes;

    if (split_ok) {
        _Float16* W2h = (_Float16*)((char*)d_ws + w2h_off);
        _Float16* W3h = (_Float16*)((char*)d_ws + w3h_off);
        uint4*    hb  = (uint4*)   ((char*)d_ws + h_off);
        hipLaunchKernelGGL(w_to_fp16, dim3(16), dim3(256), 0, stream,
                           W2, W3, W2h, W3h);
        hipLaunchKernelGGL(gather_kernel, dim3((n + RPB - 1) / RPB), dim3(256),
                           0, stream, x, (const __half*)emb16, hb, n);
        hipLaunchKernelGGL(dense_mfma, dim3((n + 63) / 64), dim3(256),
                           0, stream, (const uint4*)hb, W2h, W3h, b2, b3, W4,
                           out, n);
    } else {
        hipLaunchKernelGGL(nnue_fused, dim3((n + RPB - 1) / RPB), dim3(256),
                           0, stream, x, (const __half*)emb16, W2, b2, W3, b3,
                           W4, out, n);
    }
}

// Round 12
// 121.575 us; speedup vs baseline: 2.7106x; 1.0852x over previous
//
#include <hip/hip_runtime.h>
#include <hip/hip_fp16.h>

// SilkNNUE R11 — R10 fused design with the hT staging bug fixed.
//   R10 bug: hT row stride was 144B but a row holds 16 packets x 16B = 256B
//   -> rows overlapped -> absmax 3.8e-2. Fix: stride 272B (17 x uint4,
//   256B data + 16B pad; banks 2-way on both write and read = free).
//   To keep 6 blocks/CU: per-wave index buffer (dead after gather loop)
//   aliases the per-wave a2 transpose tile (first used after) — same-wave
//   program order makes this safe; all slices are wave-private.
// Structure (verified pieces): barrier-free gather (R7/R8) -> per-wave LDS
// h tile -> R9-verified MFMA chain (W2 -> CReLU transpose -> W3 -> W4).

typedef _Float16 h2v_t  __attribute__((ext_vector_type(2)));
typedef _Float16 half8  __attribute__((ext_vector_type(8)));
typedef float    f32x4  __attribute__((ext_vector_type(4)));

constexpr int RPB = 64;   // rows per block

__global__ __launch_bounds__(256) void emb_to_fp16(
    const float* __restrict__ emb, __half2* __restrict__ emb16,
    int npairs_real, int npairs_tot)
{
    int i = blockIdx.x * blockDim.x + threadIdx.x;
    if (i < npairs_tot) {
        float2 v = make_float2(0.f, 0.f);
        if (i < npairs_real) v = ((const float2*)emb)[i];
        emb16[i] = __floats2half2_rn(v.x, v.y);
    }
}

__global__ __launch_bounds__(256) void w_to_fp16(
    const float* __restrict__ W2, const float* __restrict__ W3,
    _Float16* __restrict__ W2h, _Float16* __restrict__ W3h)
{
    int i = blockIdx.x * blockDim.x + threadIdx.x;
    if (i < 4096) W2h[i] = (_Float16)W2[i];
    if (i < 2048) W3h[i] = (_Float16)W3[i];
}

// ---------------- fused kernel -------------------------------------------
__global__ __launch_bounds__(256, 6) void nnue_one(
    const int*      __restrict__ x,      // (N,32)
    const __half*   __restrict__ emb16,  // (7425,128), row 7424 zeros
    const _Float16* __restrict__ W2h,    // (32,128) fp16
    const _Float16* __restrict__ W3h,    // (32,64) fp16
    const float*    __restrict__ b2,
    const float*    __restrict__ b3,
    const float*    __restrict__ W4,     // (64,)
    float*          __restrict__ out, int n)
{
    // per-wave h tile: 16 rows x 17 uint4 (256B data + 16B pad per row)
    __shared__ uint4 hT[4][16 * 17];                 // 17408 B
    // per-wave scratch: indices (2048B) then a2 transpose tile (2176B), aliased
    __shared__ __align__(16) char scratch[4][2176];  //  8704 B

    const int tid  = threadIdx.x;
    const int lane = tid & 63;
    const int wave = tid >> 6;
    const int row0 = blockIdx.x * RPB;
    const int wrow0 = __builtin_amdgcn_readfirstlane(row0 + wave * 16);

    const int g   = lane >> 4;          // feature subgroup 0..3
    const int sub = lane & 15;          // 16B packet id (= 4*kk + q)
    const unsigned subOff = (unsigned)sub * 16u;

    int* xw = (int*)&scratch[wave][0];  // 16 rows x 32 idx

    // ---- stage indices (pad features 29..31 -> zero row 7424) -------------
    {
        const int4* xb = (const int4*)(x + (size_t)wrow0 * 32);
        int4 a = xb[lane * 2];
        int4 b = xb[lane * 2 + 1];
        if ((lane & 3) == 3) { b.y = 7424; b.z = 7424; b.w = 7424; }
        ((int4*)xw)[lane * 2]     = a;
        ((int4*)xw)[lane * 2 + 1] = b;
    }
    // same-wave DS ordering; no barriers anywhere in this kernel.

    // ---- gather: 8 x dwordx4 per row, packed fp16 acc, shfl combine -------
    #pragma unroll 4
    for (int r = 0; r < 16; ++r) {
        const int* xrow = &xw[r * 32 + g];
        uint4 v[8];
        #pragma unroll
        for (int b = 0; b < 8; ++b) {
            const int idx = xrow[4 * b];             // ds_read_b32 broadcast
            const unsigned off = ((unsigned)idx << 8) + subOff;
            v[b] = *(const uint4*)((const char*)emb16 + off);
        }
        h2v_t hacc[4];
        #pragma unroll
        for (int q = 0; q < 4; ++q) hacc[q] = (h2v_t)0;
        #pragma unroll
        for (int b = 0; b < 8; ++b) {
            hacc[0] += __builtin_bit_cast(h2v_t, v[b].x);
            hacc[1] += __builtin_bit_cast(h2v_t, v[b].y);
            hacc[2] += __builtin_bit_cast(h2v_t, v[b].z);
            hacc[3] += __builtin_bit_cast(h2v_t, v[b].w);
        }
        #pragma unroll
        for (int q = 0; q < 4; ++q) {
            unsigned u = __builtin_bit_cast(unsigned, hacc[q]);
            h2v_t t = __builtin_bit_cast(h2v_t, u);
            t += __builtin_bit_cast(h2v_t, (unsigned)__shfl_xor((int)u, 16));
            unsigned u2 = __builtin_bit_cast(unsigned, t);
            t += __builtin_bit_cast(h2v_t, (unsigned)__shfl_xor((int)u2, 32));
            hacc[q] = __builtin_elementwise_max(t, (h2v_t)0);
        }
        if (g == 0) {   // lanes 0..15: packet sub of row r -> hT (2-way, free)
            uint4 o;
            o.x = __builtin_bit_cast(unsigned, hacc[0]);
            o.y = __builtin_bit_cast(unsigned, hacc[1]);
            o.z = __builtin_bit_cast(unsigned, hacc[2]);
            o.w = __builtin_bit_cast(unsigned, hacc[3]);
            hT[wave][r * 17 + sub] = o;
        }
    }

    // ================= dense (per-wave MFMA, same wave's 16 rows) ==========
    const int q  = lane >> 4;     // k-quad
    const int nn = lane & 15;     // A row m / B col n / C col n

    // B-fragments for W2 (L2-hot, identical across waves)
    half8 bw2[2][4];
    #pragma unroll
    for (int nt = 0; nt < 2; ++nt)
        #pragma unroll
        for (int kk = 0; kk < 4; ++kk)
            bw2[nt][kk] = __builtin_bit_cast(half8,
                *(const uint4*)((const char*)W2h +
                    ((nt * 16 + nn) * 128 + kk * 32 + q * 8) * 2));

    // A-fragments from hT: row m = nn, packet 4*kk + q
    half8 af[4];
    #pragma unroll
    for (int kk = 0; kk < 4; ++kk)
        af[kk] = __builtin_bit_cast(half8, hT[wave][nn * 17 + (4 * kk + q)]);

    // layer 2: h2(16x32) = h(16x128) @ W2^T
    f32x4 acc0 = {0.f, 0.f, 0.f, 0.f}, acc1 = {0.f, 0.f, 0.f, 0.f};
    #pragma unroll
    for (int kk = 0; kk < 4; ++kk) {
        acc0 = __builtin_amdgcn_mfma_f32_16x16x32_f16(af[kk], bw2[0][kk], acc0, 0, 0, 0);
        acc1 = __builtin_amdgcn_mfma_f32_16x16x32_f16(af[kk], bw2[1][kk], acc1, 0, 0, 0);
    }
    const float bb0 = b2[nn], bb1 = b2[16 + nn];

    // CReLU + transpose C-layout -> A-layout via LDS (stride 68 halfs).
    // a2 aliases xw: all xw reads completed above (same-wave program order).
    _Float16* a2 = (_Float16*)&scratch[wave][0];
    #pragma unroll
    for (int r = 0; r < 4; ++r) {
        const float v0 = acc0[r] + bb0;
        const float v1 = acc1[r] + bb1;
        const int m = q * 4 + r;
        a2[m * 68 + nn]      = (_Float16)fmaxf(v0, 0.f);
        a2[m * 68 + 16 + nn] = (_Float16)fmaxf(v1, 0.f);
        a2[m * 68 + 32 + nn] = (_Float16)fmaxf(-v0, 0.f);
        a2[m * 68 + 48 + nn] = (_Float16)fmaxf(-v1, 0.f);
    }

    // B-fragments for W3
    half8 bw3[2][2];
    #pragma unroll
    for (int nt = 0; nt < 2; ++nt)
        #pragma unroll
        for (int kk = 0; kk < 2; ++kk)
            bw3[nt][kk] = __builtin_bit_cast(half8,
                *(const uint4*)((const char*)W3h +
                    ((nt * 16 + nn) * 64 + kk * 32 + q * 8) * 2));

    // A-fragments for layer 3
    half8 a2f[2];
    #pragma unroll
    for (int kk = 0; kk < 2; ++kk) {
        const _Float16* p = &a2[nn * 68 + kk * 32 + q * 8];
        half8 t;
        #pragma unroll
        for (int j = 0; j < 8; ++j) t[j] = p[j];
        a2f[kk] = t;
    }

    // layer 3: h4(16x32) = crelu(h2)(16x64) @ W3^T
    f32x4 acc30 = {0.f, 0.f, 0.f, 0.f}, acc31 = {0.f, 0.f, 0.f, 0.f};
    #pragma unroll
    for (int kk = 0; kk < 2; ++kk) {
        acc30 = __builtin_amdgcn_mfma_f32_16x16x32_f16(a2f[kk], bw3[0][kk], acc30, 0, 0, 0);
        acc31 = __builtin_amdgcn_mfma_f32_16x16x32_f16(a2f[kk], bw3[1][kk], acc31, 0, 0, 0);
    }
    const float bb30 = b3[nn], bb31 = b3[16 + nn];

    // layer 4: out[m] = crelu(h4[m]) . W4
    const float w4a = W4[nn],      w4b = W4[16 + nn];
    const float w4c = W4[32 + nn], w4d = W4[48 + nn];
    float o[4];
    #pragma unroll
    for (int r = 0; r < 4; ++r) {
        const float v0 = acc30[r] + bb30;
        const float v1 = acc31[r] + bb31;
        o[r] = fmaxf(v0, 0.f) * w4a + fmaxf(-v0, 0.f) * w4c
             + fmaxf(v1, 0.f) * w4b + fmaxf(-v1, 0.f) * w4d;
    }
    #pragma unroll
    for (int s = 1; s < 16; s <<= 1) {
        #pragma unroll
        for (int r = 0; r < 4; ++r) o[r] += __shfl_xor(o[r], s);
    }
    if (nn == 0) {
        #pragma unroll
        for (int r = 0; r < 4; ++r) {
            const int row = wrow0 + q * 4 + r;
            if (row < n) out[row] = o[r];
        }
    }
}

// ---------------- fallback (R7 fused, fp32 weights) ------------------------
__global__ __launch_bounds__(256) void nnue_fused(
    const int*    __restrict__ x,
    const __half* __restrict__ emb16,
    const float*  __restrict__ W2, const float* __restrict__ b2,
    const float*  __restrict__ W3, const float* __restrict__ b3,
    const float*  __restrict__ W4,
    float*        __restrict__ out, int n)
{
    __shared__ int     xlds[4][512];
    __shared__ __half2 hbuf[64][65];
    __shared__ float   h2T[32 * 64];
    __shared__ float   obuf[4][64];

    const int tid  = threadIdx.x;
    const int lane = tid & 63;
    const int wave = tid >> 6;
    const int row0 = blockIdx.x * RPB;
    const int wrow0 = __builtin_amdgcn_readfirstlane(row0 + wave * 16);
    const int g   = lane >> 4;
    const int sub = lane & 15;
    const unsigned subOff = (unsigned)sub * 16u;

    {
        const int4* xb = (const int4*)(x + (size_t)wrow0 * 32);
        int4 a = xb[lane * 2];
        int4 b = xb[lane * 2 + 1];
        if ((lane & 3) == 3) { b.y = 7424; b.z = 7424; b.w = 7424; }
        ((int4*)&xlds[wave][0])[lane * 2]     = a;
        ((int4*)&xlds[wave][0])[lane * 2 + 1] = b;
    }

    #pragma unroll 4
    for (int r = 0; r < 16; ++r) {
        const int* xrow = &xlds[wave][r * 32 + g];
        uint4 v[8];
        #pragma unroll
        for (int b = 0; b < 8; ++b) {
            const int idx = xrow[4 * b];
            const unsigned off = ((unsigned)idx << 8) + subOff;
            v[b] = *(const uint4*)((const char*)emb16 + off);
        }
        h2v_t hacc[4];
        #pragma unroll
        for (int q = 0; q < 4; ++q) hacc[q] = (h2v_t)0;
        #pragma unroll
        for (int b = 0; b < 8; ++b) {
            hacc[0] += __builtin_bit_cast(h2v_t, v[b].x);
            hacc[1] += __builtin_bit_cast(h2v_t, v[b].y);
            hacc[2] += __builtin_bit_cast(h2v_t, v[b].z);
            hacc[3] += __builtin_bit_cast(h2v_t, v[b].w);
        }
        #pragma unroll
        for (int q = 0; q < 4; ++q) {
            unsigned u = __builtin_bit_cast(unsigned, hacc[q]);
            h2v_t t = __builtin_bit_cast(h2v_t, u);
            t += __builtin_bit_cast(h2v_t, (unsigned)__shfl_xor((int)u, 16));
            unsigned u2 = __builtin_bit_cast(unsigned, t);
            t += __builtin_bit_cast(h2v_t, (unsigned)__shfl_xor((int)u2, 32));
            hacc[q] = __builtin_elementwise_max(t, (h2v_t)0);
        }
        if (g == 0) {
            const int row = wave * 16 + r;
            #pragma unroll
            for (int q = 0; q < 4; ++q)
                hbuf[row][sub * 4 + q] = __builtin_bit_cast(__half2, hacc[q]);
        }
    }
    __syncthreads();

    {
        const int j0 = wave * 8;
        const int rr = lane;
        float acc[8];
        #pragma unroll
        for (int j = 0; j < 8; ++j) acc[j] = b2[j0 + j];
        #pragma unroll
        for (int d2 = 0; d2 < 64; ++d2) {
            const __half2 hv = hbuf[rr][d2];
            const float vx = __low2float(hv), vy = __high2float(hv);
            #pragma unroll
            for (int j = 0; j < 8; ++j) {
                const float* w = W2 + (size_t)(j0 + j) * 128 + d2 * 2;
                acc[j] = fmaf(vx, w[0], acc[j]);
                acc[j] = fmaf(vy, w[1], acc[j]);
            }
        }
        #pragma unroll
        for (int j = 0; j < 8; ++j) h2T[(j0 + j) * 64 + rr] = acc[j];
    }
    __syncthreads();

    {
        const int j0 = wave * 8;
        const int rr = lane;
        float h2v[32];
        #pragma unroll
        for (int k = 0; k < 32; ++k) h2v[k] = h2T[k * 64 + rr];
        float acc[8];
        #pragma unroll
        for (int j = 0; j < 8; ++j) acc[j] = b3[j0 + j];
        #pragma unroll
        for (int k = 0; k < 32; ++k) {
            const float p = fmaxf(h2v[k], 0.f);
            const float m = fmaxf(-h2v[k], 0.f);
            #pragma unroll
            for (int j = 0; j < 8; ++j) {
                const float* w = W3 + (size_t)(j0 + j) * 64;
                acc[j] = fmaf(p, w[k],      acc[j]);
                acc[j] = fmaf(m, w[32 + k], acc[j]);
            }
        }
        float o = 0.f;
        #pragma unroll
        for (int j = 0; j < 8; ++j) {
            const int jj = j0 + j;
            o = fmaf(fmaxf(acc[j], 0.f),  W4[jj],      o);
            o = fmaf(fmaxf(-acc[j], 0.f), W4[32 + jj], o);
        }
        obuf[wave][rr] = o;
    }
    __syncthreads();

    if (tid < 64) {
        const int row = row0 + tid;
        if (row < n)
            out[row] = obuf[0][tid] + obuf[1][tid] + obuf[2][tid] + obuf[3][tid];
    }
}

extern "C" void kernel_launch(void* const* d_in, const int* in_sizes, int n_in,
                              void* d_out, int out_size, void* d_ws, size_t ws_size,
                              hipStream_t stream) {
    const int*   x   = (const int*)  d_in[0];
    const float* emb = (const float*)d_in[1];
    const float* W2  = (const float*)d_in[2];
    const float* b2  = (const float*)d_in[3];
    const float* W3  = (const float*)d_in[4];
    const float* b3  = (const float*)d_in[5];
    const float* W4  = (const float*)d_in[6];
    float* out = (float*)d_out;
    const int n = out_size;                 // 131072 rows

    __half2* emb16 = (__half2*)d_ws;        // 7425*256 B
    const int npairs_real = 7424 * 64;
    const int npairs_tot  = 7425 * 64;
    hipLaunchKernelGGL(emb_to_fp16, dim3((npairs_tot + 255) / 256), dim3(256),
                       0, stream, emb, emb16, npairs_real, npairs_tot);

    const size_t emb_bytes = (size_t)7425 * 256;            // 1,900,800
    const size_t w2h_off   = emb_bytes;                     // 8192 B
    const size_t w3h_off   = w2h_off + 8192;                // 4096 B
    const size_t need      = w3h_off + 4096;
    const bool   fused_ok  = ws_size >= need;

    if (fused_ok) {
        _Float16* W2h = (_Float16*)((char*)d_ws + w2h_off);
        _Float16* W3h = (_Float16*)((char*)d_ws + w3h_off);
        hipLaunchKernelGGL(w_to_fp16, dim3(16), dim3(256), 0, stream,
                           W2, W3, W2h, W3h);
        hipLaunchKernelGGL(nnue_one, dim3((n + RPB - 1) / RPB), dim3(256),
                           0, stream, x, (const __half*)emb16, W2h, W3h,
                           b2, b3, W4, out, n);
    } else {
        hipLaunchKernelGGL(nnue_fused, dim3((n + RPB - 1) / RPB), dim3(256),
                           0, stream, x, (const __half*)emb16, W2, b2, W3, b3,
                           W4, out, n);
    }
}